// Round 4
// baseline (8365.661 us; speedup 1.0000x reference)
//
#include <hip/hip_runtime.h>
#include <hip/hip_fp16.h>
#include <cstdint>

#define B_   128
#define T_   2048
#define DIN  5
#define H_   128
#define G3   384
#define D1   256
#define CH   256
#define NCH  (T_ / CH)   // 8

typedef _Float16 half8 __attribute__((ext_vector_type(8)));
typedef float f32x4 __attribute__((ext_vector_type(4)));

__device__ __forceinline__ float sigmoid_f(float x) {
    return 1.0f / (1.0f + __expf(-x));
}
__device__ __forceinline__ float tanh_f(float x) {
    return 1.0f - 2.0f / (__expf(2.0f * x) + 1.0f);
}
__device__ __forceinline__ unsigned long long pack4h(const float* h) {
    union { __half2 h2[2]; unsigned long long u; } pk;
    pk.h2[0] = __floats2half2_rn(h[0], h[1]);
    pk.h2[1] = __floats2half2_rn(h[2], h[3]);
    return pk.u;
}
__device__ __forceinline__ f32x4 h4_to_f(unsigned long long u) {
    union { unsigned long long u; __half2 h2[2]; } p; p.u = u;
    const float2 a = __half22float2(p.h2[0]);
    const float2 b = __half22float2(p.h2[1]);
    f32x4 r; r[0] = a.x; r[1] = a.y; r[2] = b.x; r[3] = b.y; return r;
}
// Barrier with LDS ordering only — no vmcnt(0) drain (keeps global loads/stores
// in flight across the barrier; __syncthreads would drain them every step).
__device__ __forceinline__ void fast_barrier() {
    asm volatile("s_waitcnt lgkmcnt(0)\n\ts_barrier" ::: "memory");
}

// ---------------------------------------------------------------------------
// scan0 v2: layer-0 GRU, MFMA. 8 blocks x 512 threads.
// Waves 0-3 = forward chain, waves 4-7 = backward chain (independent serial
// chains co-resident per SIMD for latency hiding). Math/layout identical to
// round-3: A = W~ in regs, B = [h|x|1] f16 in LDS (XOR swizzle), K=160.
// ---------------------------------------------------------------------------
__global__ __launch_bounds__(512, 2) void scan0_mfma2(
    const float* __restrict__ seq,
    const float* __restrict__ wihf, const float* __restrict__ whhf,
    const float* __restrict__ bihf, const float* __restrict__ bhhf,
    const float* __restrict__ wihb, const float* __restrict__ whhb,
    const float* __restrict__ bihb, const float* __restrict__ bhhb,
    __half* __restrict__ y0)
{
    const int tid   = threadIdx.x;
    const int chain = tid >> 8;       // 0 = fwd, 1 = bwd
    const int tl    = tid & 255;
    const int w  = tl >> 6;           // wave-in-chain 0..3
    const int l  = tl & 63;
    const int lo = l & 15;            // batch lane
    const int g  = l >> 4;            // k-group
    const int bg = blockIdx.x;        // 0..7
    const int dir = chain;

    const float* w_ih = dir ? wihb : wihf;
    const float* w_hh = dir ? whhb : whhf;
    const float* b_ih = dir ? bihb : bihf;
    const float* b_hh = dir ? bhhb : bhhf;

    __shared__ __align__(16) char smem[2 * 2 * 16 * 512];   // 32 KB
    char* base = smem + chain * 16384;

    // ---- A fragments (weights) into registers ----
    half8 a_r[2][5], a_z[2][5], a_n[2][5], a_x[2];
#pragma unroll
    for (int i = 0; i < 2; ++i) {
        const int grow = (2 * w + i) * 16 + lo;
#pragma unroll
        for (int c = 0; c < 5; ++c) {
            half8 vr, vz, vn;
#pragma unroll
            for (int j = 0; j < 8; ++j) {
                const int k = c * 32 + g * 8 + j;
                float fr, fz, fn;
                if (k < 128) {
                    fr = w_hh[grow * H_ + k];
                    fz = w_hh[(128 + grow) * H_ + k];
                    fn = w_hh[(256 + grow) * H_ + k];
                } else if (k < 133) {
                    fr = w_ih[grow * DIN + (k - 128)];
                    fz = w_ih[(128 + grow) * DIN + (k - 128)];
                    fn = 0.f;
                } else if (k == 133) {
                    fr = b_ih[grow] + b_hh[grow];
                    fz = b_ih[128 + grow] + b_hh[128 + grow];
                    fn = b_hh[256 + grow];
                } else { fr = 0.f; fz = 0.f; fn = 0.f; }
                vr[j] = (_Float16)fr; vz[j] = (_Float16)fz; vn[j] = (_Float16)fn;
            }
            a_r[i][c] = vr; a_z[i][c] = vz; a_n[i][c] = vn;
        }
        half8 vx;
#pragma unroll
        for (int j = 0; j < 8; ++j) {
            const int k = 128 + g * 8 + j;
            float f = 0.f;
            if (k < 133)       f = w_ih[(256 + grow) * DIN + (k - 128)];
            else if (k == 133) f = b_ih[256 + grow];
            vx[j] = (_Float16)f;
        }
        a_x[i] = vx;
    }

    // ---- init LDS (own chain): zero both buffers ----
#pragma unroll
    for (int q = 0; q < 4; ++q) {
        f32x4 z = {0.f, 0.f, 0.f, 0.f};
        *reinterpret_cast<f32x4*>(base + tl * 64 + q * 16) = z;
    }
    __syncthreads();
    if (tl < 32) {    // constant 1.0 at k=133 in both buffers
        const int row = tl & 15, bu = tl >> 4;
        *(_Float16*)(base + bu * 8192 + row * 512 + (266 ^ ((row & 7) << 4))) =
            (_Float16)1.0f;
    }
    const bool stager = tl < 80;
    const int sb = tl / 5, sd = tl % 5;
    const size_t seqbase = (size_t)(bg * 16 + sb) * T_ * DIN + sd;
    float x_t1 = 0.f;
    if (stager) {
        const int tt0 = dir ? (T_ - 1) : 0;
        const float x0 = seq[seqbase + (size_t)tt0 * DIN];
        *(_Float16*)(base + sb * 512 + ((256 + 2 * sd) ^ ((sb & 7) << 4))) =
            (_Float16)x0;
        const int tt1 = dir ? (T_ - 2) : 1;
        x_t1 = seq[seqbase + (size_t)tt1 * DIN];
    }
    __syncthreads();

    float h_old[2][4];
#pragma unroll
    for (int i = 0; i < 2; ++i)
#pragma unroll
        for (int q = 0; q < 4; ++q) h_old[i][q] = 0.f;

    for (int t = 0; t < T_; ++t) {
        char* cur = base + (t & 1) * 8192;
        char* nxt = base + ((t + 1) & 1) * 8192;

        // stage x[t+1] into nxt (value loaded >=1 step ago; race-free: step
        // t-1's readers of this buffer finished at the last barrier)
        if (stager)
            *(_Float16*)(nxt + sb * 512 + ((256 + 2 * sd) ^ ((sb & 7) << 4))) =
                (_Float16)x_t1;

        // B fragments from LDS (h | x | 1)
        half8 bf[5];
#pragma unroll
        for (int c = 0; c < 5; ++c)
            bf[c] = *reinterpret_cast<const half8*>(
                cur + lo * 512 + ((c * 64 + g * 16) ^ ((lo & 7) << 4)));

        // issue x[t+2] load (2 steps of slack before use)
        float x_t2 = 0.f;
        if (stager) {
            const int t2 = (t + 2 < T_) ? t + 2 : T_ - 1;
            const int tt2 = dir ? (T_ - 1 - t2) : t2;
            x_t2 = seq[seqbase + (size_t)tt2 * DIN];
        }

        f32x4 accr[2], accz[2], accn[2], accx[2];
#pragma unroll
        for (int i = 0; i < 2; ++i) {
            f32x4 zr = {0.f, 0.f, 0.f, 0.f};
            accr[i] = zr; accz[i] = zr; accn[i] = zr;
#pragma unroll
            for (int c = 0; c < 5; ++c) {
                accr[i] = __builtin_amdgcn_mfma_f32_16x16x32_f16(a_r[i][c], bf[c], accr[i], 0, 0, 0);
                accz[i] = __builtin_amdgcn_mfma_f32_16x16x32_f16(a_z[i][c], bf[c], accz[i], 0, 0, 0);
                accn[i] = __builtin_amdgcn_mfma_f32_16x16x32_f16(a_n[i][c], bf[c], accn[i], 0, 0, 0);
            }
            accx[i] = __builtin_amdgcn_mfma_f32_16x16x32_f16(a_x[i], bf[4], zr, 0, 0, 0);
        }

        const int tt = dir ? (T_ - 1 - t) : t;
#pragma unroll
        for (int i = 0; i < 2; ++i) {
            float hn[4];
#pragma unroll
            for (int q = 0; q < 4; ++q) {
                const float r = sigmoid_f(accr[i][q]);
                const float z = sigmoid_f(accz[i][q]);
                const float n = tanh_f(accx[i][q] + r * accn[i][q]);
                hn[q] = n + z * (h_old[i][q] - n);
                h_old[i][q] = hn[q];
            }
            const int j0 = (2 * w + i) * 16 + g * 4;
            const unsigned long long pu = pack4h(hn);
            *reinterpret_cast<unsigned long long*>(
                &y0[((size_t)(bg * 16 + lo) * T_ + tt) * D1 + dir * H_ + j0]) = pu;
            *reinterpret_cast<unsigned long long*>(
                nxt + lo * 512 + ((2 * j0) ^ ((lo & 7) << 4))) = pu;
        }
        x_t1 = x_t2;
        fast_barrier();
    }
}

// ---------------------------------------------------------------------------
// gemm1: one CH-long chunk of gx = y0(f16) @ W1f^T + b, f16 MFMA, f16 output.
// grid (B_*CH/128, 6), 256 threads (2x2 waves, 64x32 per wave).
// ---------------------------------------------------------------------------
__global__ __launch_bounds__(256, 2) void gemm1_f16(
    const __half* __restrict__ A,   // y0h
    const float* __restrict__ W,    // 384 x 256
    const float* __restrict__ bias, // 384
    __half* __restrict__ C,         // (B*CH) x 384, f16
    int c0)
{
    __shared__ __align__(16) _Float16 As[128][32];
    __shared__ __align__(16) _Float16 Bs[64][32];
    const int tid = threadIdx.x;
    const int wave = tid >> 6, l = tid & 63;
    const int wm = wave >> 1, wn = wave & 1;
    const int lo = l & 15, g = l >> 4;
    const int m0 = blockIdx.x * 128, n0 = blockIdx.y * 64;

    f32x4 acc[4][2];
#pragma unroll
    for (int mt = 0; mt < 4; ++mt)
#pragma unroll
        for (int nt = 0; nt < 2; ++nt) {
            f32x4 z = {0.f, 0.f, 0.f, 0.f};
            acc[mt][nt] = z;
        }

    for (int kc = 0; kc < 256; kc += 32) {
#pragma unroll
        for (int r2 = 0; r2 < 2; ++r2) {
            const int idx = tid + r2 * 256;
            const int row = idx >> 2, seg = idx & 3;
            const int m = m0 + row, bb = m >> 8, tlq = m & (CH - 1);
            const __half* src = A + ((size_t)bb * T_ + c0 + tlq) * D1 + kc + seg * 8;
            *reinterpret_cast<uint4*>(&As[row][seg * 8]) =
                *reinterpret_cast<const uint4*>(src);
        }
        {
            const int row = tid >> 2, seg = tid & 3;
            const float* srcw = W + (size_t)(n0 + row) * D1 + kc + seg * 8;
            const float4 u0 = *reinterpret_cast<const float4*>(srcw);
            const float4 u1 = *reinterpret_cast<const float4*>(srcw + 4);
            half8 hv;
            hv[0] = (_Float16)u0.x; hv[1] = (_Float16)u0.y;
            hv[2] = (_Float16)u0.z; hv[3] = (_Float16)u0.w;
            hv[4] = (_Float16)u1.x; hv[5] = (_Float16)u1.y;
            hv[6] = (_Float16)u1.z; hv[7] = (_Float16)u1.w;
            *reinterpret_cast<half8*>(&Bs[row][seg * 8]) = hv;
        }
        __syncthreads();
        half8 af[4], bfr[2];
#pragma unroll
        for (int mt = 0; mt < 4; ++mt)
            af[mt] = *reinterpret_cast<half8*>(&As[wm * 64 + mt * 16 + lo][g * 8]);
#pragma unroll
        for (int nt = 0; nt < 2; ++nt)
            bfr[nt] = *reinterpret_cast<half8*>(&Bs[wn * 32 + nt * 16 + lo][g * 8]);
#pragma unroll
        for (int mt = 0; mt < 4; ++mt)
#pragma unroll
            for (int nt = 0; nt < 2; ++nt)
                acc[mt][nt] = __builtin_amdgcn_mfma_f32_16x16x32_f16(
                    af[mt], bfr[nt], acc[mt][nt], 0, 0, 0);
        __syncthreads();
    }
#pragma unroll
    for (int nt = 0; nt < 2; ++nt) {
        const int n = n0 + wn * 32 + nt * 16 + lo;
        const float bv = bias[n];
#pragma unroll
        for (int mt = 0; mt < 4; ++mt) {
            const int mrow = m0 + wm * 64 + mt * 16 + g * 4;
#pragma unroll
            for (int q = 0; q < 4; ++q)
                C[(size_t)(mrow + q) * G3 + n] = __float2half(acc[mt][nt][q] + bv);
        }
    }
}

// ---------------------------------------------------------------------------
// scan1 v2: layer-1 forward over one CH chunk. 4 blocks x 512 threads:
// waves 0-3 = batch-group 2*blk, waves 4-7 = batch-group 2*blk+1 (independent
// chains). gx (incl. b_ih) precomputed f16; b_hh added in epilogue.
// ---------------------------------------------------------------------------
__global__ __launch_bounds__(512, 2) void scan1_mfma2(
    const __half* __restrict__ gxc,  // [B][CH][384] f16 (chunk-local t)
    const float* __restrict__ whh, const float* __restrict__ bhh,
    float* __restrict__ h1, int c)
{
    const int tid = threadIdx.x;
    const int sub = tid >> 8;        // chain-in-block
    const int tl  = tid & 255;
    const int w = tl >> 6, l = tl & 63;
    const int lo = l & 15, g = l >> 4;
    const int grp = blockIdx.x * 2 + sub;   // 0..7

    __shared__ __align__(16) char smem[2 * 2 * 16 * 256];   // 16 KB
    char* base = smem + sub * 8192;

    half8 a_r[2][4], a_z[2][4], a_n[2][4];
    float br[2][4], bz[2][4], bn[2][4];
#pragma unroll
    for (int i = 0; i < 2; ++i) {
        const int grow = (2 * w + i) * 16 + lo;
#pragma unroll
        for (int cc = 0; cc < 4; ++cc) {
            half8 vr, vz, vn;
#pragma unroll
            for (int j = 0; j < 8; ++j) {
                const int k = cc * 32 + g * 8 + j;
                vr[j] = (_Float16)whh[grow * H_ + k];
                vz[j] = (_Float16)whh[(128 + grow) * H_ + k];
                vn[j] = (_Float16)whh[(256 + grow) * H_ + k];
            }
            a_r[i][cc] = vr; a_z[i][cc] = vz; a_n[i][cc] = vn;
        }
#pragma unroll
        for (int q = 0; q < 4; ++q) {
            const int gq = (2 * w + i) * 16 + g * 4 + q;
            br[i][q] = bhh[gq];
            bz[i][q] = bhh[128 + gq];
            bn[i][q] = bhh[256 + gq];
        }
    }

#pragma unroll
    for (int q = 0; q < 2; ++q) {
        f32x4 z = {0.f, 0.f, 0.f, 0.f};
        *reinterpret_cast<f32x4*>(base + tl * 32 + q * 16) = z;
    }
    __syncthreads();

    float h_old[2][4];
    if (c == 0) {
#pragma unroll
        for (int i = 0; i < 2; ++i)
#pragma unroll
            for (int q = 0; q < 4; ++q) h_old[i][q] = 0.f;
    } else {
#pragma unroll
        for (int i = 0; i < 2; ++i) {
            const int j0 = (2 * w + i) * 16 + g * 4;
            const f32x4 hv = *reinterpret_cast<const f32x4*>(
                &h1[(grp * 16 + lo) * H_ + j0]);
            float hn[4];
#pragma unroll
            for (int q = 0; q < 4; ++q) { h_old[i][q] = hv[q]; hn[q] = hv[q]; }
            *reinterpret_cast<unsigned long long*>(
                base + lo * 256 + ((2 * j0) ^ ((lo & 7) << 4))) = pack4h(hn);
        }
    }
    __syncthreads();

    const __half* gxl = gxc + (size_t)(grp * 16 + lo) * CH * G3;
    unsigned long long gxc_cur[6], gxc_nxt[6];
#pragma unroll
    for (int i = 0; i < 2; ++i) {
        const int gr0 = (2 * w + i) * 16 + g * 4;
        gxc_cur[i]     = *reinterpret_cast<const unsigned long long*>(gxl + gr0);
        gxc_cur[2 + i] = *reinterpret_cast<const unsigned long long*>(gxl + 128 + gr0);
        gxc_cur[4 + i] = *reinterpret_cast<const unsigned long long*>(gxl + 256 + gr0);
    }

    for (int t = 0; t < CH; ++t) {
        char* curb = base + (t & 1) * 4096;
        char* nxtb = base + ((t + 1) & 1) * 4096;

        half8 bf[4];
#pragma unroll
        for (int cc = 0; cc < 4; ++cc)
            bf[cc] = *reinterpret_cast<const half8*>(
                curb + lo * 256 + ((cc * 64 + g * 16) ^ ((lo & 7) << 4)));

        // prefetch next step's gx (global, stays in flight across barrier)
        const int tn = (t + 1 < CH) ? t + 1 : t;
        const __half* p = gxl + (size_t)tn * G3;
#pragma unroll
        for (int i = 0; i < 2; ++i) {
            const int gr0 = (2 * w + i) * 16 + g * 4;
            gxc_nxt[i]     = *reinterpret_cast<const unsigned long long*>(p + gr0);
            gxc_nxt[2 + i] = *reinterpret_cast<const unsigned long long*>(p + 128 + gr0);
            gxc_nxt[4 + i] = *reinterpret_cast<const unsigned long long*>(p + 256 + gr0);
        }

        f32x4 accr[2], accz[2], accn[2];
#pragma unroll
        for (int i = 0; i < 2; ++i) {
            f32x4 zr = {0.f, 0.f, 0.f, 0.f};
            accr[i] = zr; accz[i] = zr; accn[i] = zr;
#pragma unroll
            for (int cc = 0; cc < 4; ++cc) {
                accr[i] = __builtin_amdgcn_mfma_f32_16x16x32_f16(a_r[i][cc], bf[cc], accr[i], 0, 0, 0);
                accz[i] = __builtin_amdgcn_mfma_f32_16x16x32_f16(a_z[i][cc], bf[cc], accz[i], 0, 0, 0);
                accn[i] = __builtin_amdgcn_mfma_f32_16x16x32_f16(a_n[i][cc], bf[cc], accn[i], 0, 0, 0);
            }
        }

#pragma unroll
        for (int i = 0; i < 2; ++i) {
            const f32x4 gr = h4_to_f(gxc_cur[i]);
            const f32x4 gz = h4_to_f(gxc_cur[2 + i]);
            const f32x4 gn = h4_to_f(gxc_cur[4 + i]);
            float hn[4];
#pragma unroll
            for (int q = 0; q < 4; ++q) {
                const float r = sigmoid_f(accr[i][q] + br[i][q] + gr[q]);
                const float z = sigmoid_f(accz[i][q] + bz[i][q] + gz[q]);
                const float n = tanh_f(gn[q] + r * (accn[i][q] + bn[i][q]));
                hn[q] = n + z * (h_old[i][q] - n);
                h_old[i][q] = hn[q];
            }
            const int j0 = (2 * w + i) * 16 + g * 4;
            *reinterpret_cast<unsigned long long*>(
                nxtb + lo * 256 + ((2 * j0) ^ ((lo & 7) << 4))) = pack4h(hn);
        }
#pragma unroll
        for (int i = 0; i < 6; ++i) gxc_cur[i] = gxc_nxt[i];
        fast_barrier();
    }

#pragma unroll
    for (int i = 0; i < 2; ++i) {
        const int j0 = (2 * w + i) * 16 + g * 4;
        f32x4 hv;
#pragma unroll
        for (int q = 0; q < 4; ++q) hv[q] = h_old[i][q];
        *reinterpret_cast<f32x4*>(&h1[(grp * 16 + lo) * H_ + j0]) = hv;
    }
}

// ---------------------------------------------------------------------------
// Layer-1 backward single step at t=T-1 (h0=0 -> gh=b_hh) + FC head.
// ---------------------------------------------------------------------------
__global__ __launch_bounds__(384, 1) void back1_fc(
    const __half* __restrict__ y0, const float* __restrict__ h1,
    const float* __restrict__ w_ih_1b, const float* __restrict__ b_ih_1b,
    const float* __restrict__ b_hh_1b,
    const float* __restrict__ fc_w, const float* __restrict__ fc_b,
    float* __restrict__ out)
{
    const int g = threadIdx.x;
    const int b = blockIdx.x;
    __shared__ float ylast[D1];
    __shared__ float pre_rz[2 * H_];
    __shared__ float gxn[H_], ghn[H_];
    __shared__ float hb[H_];
    __shared__ float red[H_];

    if (g < D1) ylast[g] = __half2float(y0[((size_t)b * T_ + (T_ - 1)) * D1 + g]);
    __syncthreads();

    float accb = b_ih_1b[g];
    const float* wrow = w_ih_1b + (size_t)g * D1;
#pragma unroll 8
    for (int k = 0; k < D1; k += 4) {
        const float4 v = *reinterpret_cast<const float4*>(&ylast[k]);
        const float4 wv = *reinterpret_cast<const float4*>(&wrow[k]);
        accb += v.x * wv.x + v.y * wv.y + v.z * wv.z + v.w * wv.w;
    }
    const float bh2 = b_hh_1b[g];
    if (g < 2 * H_) pre_rz[g] = accb + bh2;
    else            { gxn[g - 2 * H_] = accb; ghn[g - 2 * H_] = bh2; }
    __syncthreads();
    if (g < H_) {
        const float r = sigmoid_f(pre_rz[g]);
        const float z = sigmoid_f(pre_rz[g + H_]);
        const float n = tanh_f(gxn[g] + r * ghn[g]);
        hb[g] = (1.0f - z) * n;
    }
    __syncthreads();
    if (g < H_) red[g] = h1[b * H_ + g] * fc_w[g] + hb[g] * fc_w[H_ + g];
    __syncthreads();
    if (g == 0) {
        float s = fc_b[0];
#pragma unroll 8
        for (int k = 0; k < H_; ++k) s += red[k];
        out[b] = s;
    }
}

// ---------------------------------------------------------------------------
extern "C" void kernel_launch(void* const* d_in, const int* in_sizes, int n_in,
                              void* d_out, int out_size, void* d_ws, size_t ws_size,
                              hipStream_t stream)
{
    const float* seq      = (const float*)d_in[0];
    const float* w_ih_l0f = (const float*)d_in[1];
    const float* w_hh_l0f = (const float*)d_in[2];
    const float* b_ih_l0f = (const float*)d_in[3];
    const float* b_hh_l0f = (const float*)d_in[4];
    const float* w_ih_l0b = (const float*)d_in[5];
    const float* w_hh_l0b = (const float*)d_in[6];
    const float* b_ih_l0b = (const float*)d_in[7];
    const float* b_hh_l0b = (const float*)d_in[8];
    const float* w_ih_l1f = (const float*)d_in[9];
    const float* w_hh_l1f = (const float*)d_in[10];
    const float* b_ih_l1f = (const float*)d_in[11];
    const float* b_hh_l1f = (const float*)d_in[12];
    const float* w_ih_l1b = (const float*)d_in[13];
    // d_in[14] = w_hh_l1b unused: only t=T-1 of the reversed layer-1 backward
    // is needed, and there h0=0 -> gh = b_hh_l1b.
    const float* b_ih_l1b = (const float*)d_in[15];
    const float* b_hh_l1b = (const float*)d_in[16];
    const float* fc_w     = (const float*)d_in[17];
    const float* fc_b     = (const float*)d_in[18];
    float* out = (float*)d_out;

    __half* y0h = (__half*)d_ws;                               // 128 MiB
    __half* gxc = (__half*)((char*)d_ws +
                  (size_t)B_ * T_ * D1 * sizeof(__half));      // 24 MiB (f16)
    float*  h1  = (float*)(gxc + (size_t)B_ * CH * G3);        // 64 KiB

    hipLaunchKernelGGL(scan0_mfma2, dim3(8), dim3(512), 0, stream,
        seq, w_ih_l0f, w_hh_l0f, b_ih_l0f, b_hh_l0f,
             w_ih_l0b, w_hh_l0b, b_ih_l0b, b_hh_l0b, y0h);

    for (int ci = 0; ci < NCH; ++ci) {
        hipLaunchKernelGGL(gemm1_f16, dim3(B_ * CH / 128, 6), dim3(256), 0, stream,
            y0h, w_ih_l1f, b_ih_l1f, gxc, ci * CH);
        hipLaunchKernelGGL(scan1_mfma2, dim3(4), dim3(512), 0, stream,
            gxc, w_hh_l1f, b_hh_l1f, h1, ci);
    }

    hipLaunchKernelGGL(back1_fc, dim3(B_), dim3(384), 0, stream,
        y0h, h1, w_ih_l1b, b_ih_l1b, b_hh_l1b, fc_w, fc_b, out);
}

// Round 6
// 3665.662 us; speedup vs baseline: 2.2822x; 2.2822x over previous
//
#include <hip/hip_runtime.h>
#include <hip/hip_fp16.h>
#include <cstdint>

#define B_   128
#define T_   2048
#define DIN  5
#define H_   128
#define G3   384
#define D1   256
#define CH   256
#define NCH  (T_ / CH)   // 8

typedef _Float16 half8 __attribute__((ext_vector_type(8)));
typedef float f32x4 __attribute__((ext_vector_type(4)));

// raw v_rcp_f32 (~1 ulp) — avoids the precise-div v_div_* sequence
__device__ __forceinline__ float sigmoid_f(float x) {
    return __builtin_amdgcn_rcpf(1.0f + __expf(-x));
}
__device__ __forceinline__ float tanh_f(float x) {
    return 1.0f - 2.0f * __builtin_amdgcn_rcpf(__expf(2.0f * x) + 1.0f);
}
__device__ __forceinline__ unsigned long long pack4h(const float* h) {
    union { __half2 h2[2]; unsigned long long u; } pk;
    pk.h2[0] = __floats2half2_rn(h[0], h[1]);
    pk.h2[1] = __floats2half2_rn(h[2], h[3]);
    return pk.u;
}
__device__ __forceinline__ f32x4 h4_to_f(unsigned long long u) {
    union { unsigned long long u; __half2 h2[2]; } p; p.u = u;
    const float2 a = __half22float2(p.h2[0]);
    const float2 b = __half22float2(p.h2[1]);
    f32x4 r; r[0] = a.x; r[1] = a.y; r[2] = b.x; r[3] = b.y; return r;
}
// Barrier with LDS ordering only — no vmcnt(0) drain (keeps global loads and
// the scattered y0 stores in flight across the barrier).
__device__ __forceinline__ void fast_barrier() {
    asm volatile("s_waitcnt lgkmcnt(0)\n\ts_barrier" ::: "memory");
}

// ---------------------------------------------------------------------------
// scan0: layer-0 GRU, MFMA. 16 blocks x 256 threads, ONE chain per block
// (private LDS pipe per chain). Waves 0-3 split the 384 gate rows.
// A = W~ in regs, B = [h|x|1] f16 in LDS (XOR swizzle), K=160.
// ---------------------------------------------------------------------------
__global__ __launch_bounds__(256, 1) void scan0_mfma3(
    const float* __restrict__ seq,
    const float* __restrict__ wihf, const float* __restrict__ whhf,
    const float* __restrict__ bihf, const float* __restrict__ bhhf,
    const float* __restrict__ wihb, const float* __restrict__ whhb,
    const float* __restrict__ bihb, const float* __restrict__ bhhb,
    __half* __restrict__ y0)
{
    const int tid = threadIdx.x;
    const int w  = tid >> 6;          // wave 0..3
    const int l  = tid & 63;
    const int lo = l & 15;            // batch lane
    const int g  = l >> 4;            // k-group
    const int dir = blockIdx.x >> 3;  // 0 fwd, 1 bwd
    const int bg  = blockIdx.x & 7;

    const float* w_ih = dir ? wihb : wihf;
    const float* w_hh = dir ? whhb : whhf;
    const float* b_ih = dir ? bihb : bihf;
    const float* b_hh = dir ? bhhb : bhhf;

    __shared__ __align__(16) char smem[2 * 16 * 512];   // 16 KB

    // ---- A fragments (weights) into registers ----
    half8 a_r[2][5], a_z[2][5], a_n[2][5], a_x[2];
#pragma unroll
    for (int i = 0; i < 2; ++i) {
        const int grow = (2 * w + i) * 16 + lo;
#pragma unroll
        for (int c = 0; c < 5; ++c) {
            half8 vr, vz, vn;
#pragma unroll
            for (int j = 0; j < 8; ++j) {
                const int k = c * 32 + g * 8 + j;
                float fr, fz, fn;
                if (k < 128) {
                    fr = w_hh[grow * H_ + k];
                    fz = w_hh[(128 + grow) * H_ + k];
                    fn = w_hh[(256 + grow) * H_ + k];
                } else if (k < 133) {
                    fr = w_ih[grow * DIN + (k - 128)];
                    fz = w_ih[(128 + grow) * DIN + (k - 128)];
                    fn = 0.f;
                } else if (k == 133) {
                    fr = b_ih[grow] + b_hh[grow];
                    fz = b_ih[128 + grow] + b_hh[128 + grow];
                    fn = b_hh[256 + grow];
                } else { fr = 0.f; fz = 0.f; fn = 0.f; }
                vr[j] = (_Float16)fr; vz[j] = (_Float16)fz; vn[j] = (_Float16)fn;
            }
            a_r[i][c] = vr; a_z[i][c] = vz; a_n[i][c] = vn;
        }
        half8 vx;
#pragma unroll
        for (int j = 0; j < 8; ++j) {
            const int k = 128 + g * 8 + j;
            float f = 0.f;
            if (k < 133)       f = w_ih[(256 + grow) * DIN + (k - 128)];
            else if (k == 133) f = b_ih[256 + grow];
            vx[j] = (_Float16)f;
        }
        a_x[i] = vx;
    }

    // ---- init LDS: zero both buffers ----
#pragma unroll
    for (int q = 0; q < 4; ++q) {
        f32x4 z = {0.f, 0.f, 0.f, 0.f};
        *reinterpret_cast<f32x4*>(smem + tid * 64 + q * 16) = z;
    }
    __syncthreads();
    if (tid < 32) {    // constant 1.0 at k=133 in both buffers
        const int row = tid & 15, bu = tid >> 4;
        *(_Float16*)(smem + bu * 8192 + row * 512 + (266 ^ ((row & 7) << 4))) =
            (_Float16)1.0f;
    }
    const bool stager = tid < 80;
    const int sb = tid / 5, sd = tid % 5;
    const size_t seqbase = (size_t)(bg * 16 + sb) * T_ * DIN + sd;
    float x_t1 = 0.f;
    if (stager) {
        const int tt0 = dir ? (T_ - 1) : 0;
        const float x0 = seq[seqbase + (size_t)tt0 * DIN];
        *(_Float16*)(smem + sb * 512 + ((256 + 2 * sd) ^ ((sb & 7) << 4))) =
            (_Float16)x0;
        const int tt1 = dir ? (T_ - 2) : 1;
        x_t1 = seq[seqbase + (size_t)tt1 * DIN];
    }
    __syncthreads();

    float h_old[2][4];
#pragma unroll
    for (int i = 0; i < 2; ++i)
#pragma unroll
        for (int q = 0; q < 4; ++q) h_old[i][q] = 0.f;

    for (int t = 0; t < T_; ++t) {
        char* cur = smem + (t & 1) * 8192;
        char* nxt = smem + ((t + 1) & 1) * 8192;

        // stage x[t+1] into nxt (value loaded >=1 step ago; step t-1's readers
        // of this buffer finished at the last barrier)
        if (stager)
            *(_Float16*)(nxt + sb * 512 + ((256 + 2 * sd) ^ ((sb & 7) << 4))) =
                (_Float16)x_t1;

        // B fragments from LDS (h | x | 1)
        half8 bf[5];
#pragma unroll
        for (int c = 0; c < 5; ++c)
            bf[c] = *reinterpret_cast<const half8*>(
                cur + lo * 512 + ((c * 64 + g * 16) ^ ((lo & 7) << 4)));

        // issue x[t+2] load (2 steps of slack before use)
        float x_t2 = 0.f;
        if (stager) {
            const int t2 = (t + 2 < T_) ? t + 2 : T_ - 1;
            const int tt2 = dir ? (T_ - 1 - t2) : t2;
            x_t2 = seq[seqbase + (size_t)tt2 * DIN];
        }

        f32x4 accr[2], accz[2], accn[2], accx[2];
#pragma unroll
        for (int i = 0; i < 2; ++i) {
            f32x4 zr = {0.f, 0.f, 0.f, 0.f};
            accr[i] = zr; accz[i] = zr; accn[i] = zr;
#pragma unroll
            for (int c = 0; c < 5; ++c) {
                accr[i] = __builtin_amdgcn_mfma_f32_16x16x32_f16(a_r[i][c], bf[c], accr[i], 0, 0, 0);
                accz[i] = __builtin_amdgcn_mfma_f32_16x16x32_f16(a_z[i][c], bf[c], accz[i], 0, 0, 0);
                accn[i] = __builtin_amdgcn_mfma_f32_16x16x32_f16(a_n[i][c], bf[c], accn[i], 0, 0, 0);
            }
            accx[i] = __builtin_amdgcn_mfma_f32_16x16x32_f16(a_x[i], bf[4], zr, 0, 0, 0);
        }

        const int tt = dir ? (T_ - 1 - t) : t;
#pragma unroll
        for (int i = 0; i < 2; ++i) {
            float hn[4];
#pragma unroll
            for (int q = 0; q < 4; ++q) {
                const float r = sigmoid_f(accr[i][q]);
                const float z = sigmoid_f(accz[i][q]);
                const float n = tanh_f(accx[i][q] + r * accn[i][q]);
                hn[q] = n + z * (h_old[i][q] - n);
                h_old[i][q] = hn[q];
            }
            const int j0 = (2 * w + i) * 16 + g * 4;
            const unsigned long long pu = pack4h(hn);
            *reinterpret_cast<unsigned long long*>(
                &y0[((size_t)(bg * 16 + lo) * T_ + tt) * D1 + dir * H_ + j0]) = pu;
            *reinterpret_cast<unsigned long long*>(
                nxt + lo * 512 + ((2 * j0) ^ ((lo & 7) << 4))) = pu;
        }
        x_t1 = x_t2;
        fast_barrier();
    }
}

// ---------------------------------------------------------------------------
// gemm1: one CH-long chunk of gx = y0(f16) @ W1f^T + b, f16 MFMA, f16 output.
// grid (B_*CH/128, 6), 256 threads (2x2 waves, 64x32 per wave).
// ---------------------------------------------------------------------------
__global__ __launch_bounds__(256, 2) void gemm1_f16(
    const __half* __restrict__ A,   // y0h
    const float* __restrict__ W,    // 384 x 256
    const float* __restrict__ bias, // 384
    __half* __restrict__ C,         // (B*CH) x 384, f16
    int c0)
{
    __shared__ __align__(16) _Float16 As[128][32];
    __shared__ __align__(16) _Float16 Bs[64][32];
    const int tid = threadIdx.x;
    const int wave = tid >> 6, l = tid & 63;
    const int wm = wave >> 1, wn = wave & 1;
    const int lo = l & 15, g = l >> 4;
    const int m0 = blockIdx.x * 128, n0 = blockIdx.y * 64;

    f32x4 acc[4][2];
#pragma unroll
    for (int mt = 0; mt < 4; ++mt)
#pragma unroll
        for (int nt = 0; nt < 2; ++nt) {
            f32x4 z = {0.f, 0.f, 0.f, 0.f};
            acc[mt][nt] = z;
        }

    for (int kc = 0; kc < 256; kc += 32) {
#pragma unroll
        for (int r2 = 0; r2 < 2; ++r2) {
            const int idx = tid + r2 * 256;
            const int row = idx >> 2, seg = idx & 3;
            const int m = m0 + row, bb = m >> 8, tlq = m & (CH - 1);
            const __half* src = A + ((size_t)bb * T_ + c0 + tlq) * D1 + kc + seg * 8;
            *reinterpret_cast<uint4*>(&As[row][seg * 8]) =
                *reinterpret_cast<const uint4*>(src);
        }
        {
            const int row = tid >> 2, seg = tid & 3;
            const float* srcw = W + (size_t)(n0 + row) * D1 + kc + seg * 8;
            const float4 u0 = *reinterpret_cast<const float4*>(srcw);
            const float4 u1 = *reinterpret_cast<const float4*>(srcw + 4);
            half8 hv;
            hv[0] = (_Float16)u0.x; hv[1] = (_Float16)u0.y;
            hv[2] = (_Float16)u0.z; hv[3] = (_Float16)u0.w;
            hv[4] = (_Float16)u1.x; hv[5] = (_Float16)u1.y;
            hv[6] = (_Float16)u1.z; hv[7] = (_Float16)u1.w;
            *reinterpret_cast<half8*>(&Bs[row][seg * 8]) = hv;
        }
        __syncthreads();
        half8 af[4], bfr[2];
#pragma unroll
        for (int mt = 0; mt < 4; ++mt)
            af[mt] = *reinterpret_cast<half8*>(&As[wm * 64 + mt * 16 + lo][g * 8]);
#pragma unroll
        for (int nt = 0; nt < 2; ++nt)
            bfr[nt] = *reinterpret_cast<half8*>(&Bs[wn * 32 + nt * 16 + lo][g * 8]);
#pragma unroll
        for (int mt = 0; mt < 4; ++mt)
#pragma unroll
            for (int nt = 0; nt < 2; ++nt)
                acc[mt][nt] = __builtin_amdgcn_mfma_f32_16x16x32_f16(
                    af[mt], bfr[nt], acc[mt][nt], 0, 0, 0);
        __syncthreads();
    }
#pragma unroll
    for (int nt = 0; nt < 2; ++nt) {
        const int n = n0 + wn * 32 + nt * 16 + lo;
        const float bv = bias[n];
#pragma unroll
        for (int mt = 0; mt < 4; ++mt) {
            const int mrow = m0 + wm * 64 + mt * 16 + g * 4;
#pragma unroll
            for (int q = 0; q < 4; ++q)
                C[(size_t)(mrow + q) * G3 + n] = __float2half(acc[mt][nt][q] + bv);
        }
    }
}

// ---------------------------------------------------------------------------
// scan1: layer-1 forward over one CH chunk. 8 blocks x 256 threads, one
// batch-group chain per block. gx (incl. b_ih) precomputed f16.
// ---------------------------------------------------------------------------
__global__ __launch_bounds__(256, 1) void scan1_mfma3(
    const __half* __restrict__ gxc,  // [B][CH][384] f16 (chunk-local t)
    const float* __restrict__ whh, const float* __restrict__ bhh,
    float* __restrict__ h1, int c)
{
    const int tid = threadIdx.x;
    const int w = tid >> 6, l = tid & 63;
    const int lo = l & 15, g = l >> 4;
    const int grp = blockIdx.x;      // 0..7

    __shared__ __align__(16) char smem[2 * 16 * 256];   // 8 KB

    half8 a_r[2][4], a_z[2][4], a_n[2][4];
    float br[2][4], bz[2][4], bn[2][4];
#pragma unroll
    for (int i = 0; i < 2; ++i) {
        const int grow = (2 * w + i) * 16 + lo;
#pragma unroll
        for (int cc = 0; cc < 4; ++cc) {
            half8 vr, vz, vn;
#pragma unroll
            for (int j = 0; j < 8; ++j) {
                const int k = cc * 32 + g * 8 + j;
                vr[j] = (_Float16)whh[grow * H_ + k];
                vz[j] = (_Float16)whh[(128 + grow) * H_ + k];
                vn[j] = (_Float16)whh[(256 + grow) * H_ + k];
            }
            a_r[i][cc] = vr; a_z[i][cc] = vz; a_n[i][cc] = vn;
        }
#pragma unroll
        for (int q = 0; q < 4; ++q) {
            const int gq = (2 * w + i) * 16 + g * 4 + q;
            br[i][q] = bhh[gq];
            bz[i][q] = bhh[128 + gq];
            bn[i][q] = bhh[256 + gq];
        }
    }

#pragma unroll
    for (int q = 0; q < 2; ++q) {
        f32x4 z = {0.f, 0.f, 0.f, 0.f};
        *reinterpret_cast<f32x4*>(smem + tid * 32 + q * 16) = z;
    }
    __syncthreads();

    float h_old[2][4];
    if (c == 0) {
#pragma unroll
        for (int i = 0; i < 2; ++i)
#pragma unroll
            for (int q = 0; q < 4; ++q) h_old[i][q] = 0.f;
    } else {
#pragma unroll
        for (int i = 0; i < 2; ++i) {
            const int j0 = (2 * w + i) * 16 + g * 4;
            const f32x4 hv = *reinterpret_cast<const f32x4*>(
                &h1[(grp * 16 + lo) * H_ + j0]);
            float hn[4];
#pragma unroll
            for (int q = 0; q < 4; ++q) { h_old[i][q] = hv[q]; hn[q] = hv[q]; }
            *reinterpret_cast<unsigned long long*>(
                smem + lo * 256 + ((2 * j0) ^ ((lo & 7) << 4))) = pack4h(hn);
        }
    }
    __syncthreads();

    const __half* gxl = gxc + (size_t)(grp * 16 + lo) * CH * G3;
    unsigned long long gxc_cur[6], gxc_nxt[6];
#pragma unroll
    for (int i = 0; i < 2; ++i) {
        const int gr0 = (2 * w + i) * 16 + g * 4;
        gxc_cur[i]     = *reinterpret_cast<const unsigned long long*>(gxl + gr0);
        gxc_cur[2 + i] = *reinterpret_cast<const unsigned long long*>(gxl + 128 + gr0);
        gxc_cur[4 + i] = *reinterpret_cast<const unsigned long long*>(gxl + 256 + gr0);
    }

    for (int t = 0; t < CH; ++t) {
        char* curb = smem + (t & 1) * 4096;
        char* nxtb = smem + ((t + 1) & 1) * 4096;

        half8 bf[4];
#pragma unroll
        for (int cc = 0; cc < 4; ++cc)
            bf[cc] = *reinterpret_cast<const half8*>(
                curb + lo * 256 + ((cc * 64 + g * 16) ^ ((lo & 7) << 4)));

        // prefetch next step's gx (global, stays in flight across barrier)
        const int tn = (t + 1 < CH) ? t + 1 : t;
        const __half* p = gxl + (size_t)tn * G3;
#pragma unroll
        for (int i = 0; i < 2; ++i) {
            const int gr0 = (2 * w + i) * 16 + g * 4;
            gxc_nxt[i]     = *reinterpret_cast<const unsigned long long*>(p + gr0);
            gxc_nxt[2 + i] = *reinterpret_cast<const unsigned long long*>(p + 128 + gr0);
            gxc_nxt[4 + i] = *reinterpret_cast<const unsigned long long*>(p + 256 + gr0);
        }

        f32x4 accr[2], accz[2], accn[2];
#pragma unroll
        for (int i = 0; i < 2; ++i) {
            f32x4 zr = {0.f, 0.f, 0.f, 0.f};
            accr[i] = zr; accz[i] = zr; accn[i] = zr;
#pragma unroll
            for (int cc = 0; cc < 4; ++cc) {
                accr[i] = __builtin_amdgcn_mfma_f32_16x16x32_f16(a_r[i][cc], bf[cc], accr[i], 0, 0, 0);
                accz[i] = __builtin_amdgcn_mfma_f32_16x16x32_f16(a_z[i][cc], bf[cc], accz[i], 0, 0, 0);
                accn[i] = __builtin_amdgcn_mfma_f32_16x16x32_f16(a_n[i][cc], bf[cc], accn[i], 0, 0, 0);
            }
        }

#pragma unroll
        for (int i = 0; i < 2; ++i) {
            const f32x4 gr = h4_to_f(gxc_cur[i]);
            const f32x4 gz = h4_to_f(gxc_cur[2 + i]);
            const f32x4 gn = h4_to_f(gxc_cur[4 + i]);
            float hn[4];
#pragma unroll
            for (int q = 0; q < 4; ++q) {
                const float r = sigmoid_f(accr[i][q] + br[i][q] + gr[q]);
                const float z = sigmoid_f(accz[i][q] + bz[i][q] + gz[q]);
                const float n = tanh_f(gn[q] + r * (accn[i][q] + bn[i][q]));
                hn[q] = n + z * (h_old[i][q] - n);
                h_old[i][q] = hn[q];
            }
            const int j0 = (2 * w + i) * 16 + g * 4;
            *reinterpret_cast<unsigned long long*>(
                nxtb + lo * 256 + ((2 * j0) ^ ((lo & 7) << 4))) = pack4h(hn);
        }
#pragma unroll
        for (int i = 0; i < 6; ++i) gxc_cur[i] = gxc_nxt[i];
        fast_barrier();
    }

#pragma unroll
    for (int i = 0; i < 2; ++i) {
        const int j0 = (2 * w + i) * 16 + g * 4;
        f32x4 hv;
#pragma unroll
        for (int q = 0; q < 4; ++q) hv[q] = h_old[i][q];
        *reinterpret_cast<f32x4*>(&h1[(grp * 16 + lo) * H_ + j0]) = hv;
    }
}

// ---------------------------------------------------------------------------
// Layer-1 backward single step at t=T-1 (h0=0 -> gh=b_hh) + FC head.
// ---------------------------------------------------------------------------
__global__ __launch_bounds__(384, 1) void back1_fc(
    const __half* __restrict__ y0, const float* __restrict__ h1,
    const float* __restrict__ w_ih_1b, const float* __restrict__ b_ih_1b,
    const float* __restrict__ b_hh_1b,
    const float* __restrict__ fc_w, const float* __restrict__ fc_b,
    float* __restrict__ out)
{
    const int g = threadIdx.x;
    const int b = blockIdx.x;
    __shared__ float ylast[D1];
    __shared__ float pre_rz[2 * H_];
    __shared__ float gxn[H_], ghn[H_];
    __shared__ float hb[H_];
    __shared__ float red[H_];

    if (g < D1) ylast[g] = __half2float(y0[((size_t)b * T_ + (T_ - 1)) * D1 + g]);
    __syncthreads();

    float accb = b_ih_1b[g];
    const float* wrow = w_ih_1b + (size_t)g * D1;
#pragma unroll 8
    for (int k = 0; k < D1; k += 4) {
        const float4 v = *reinterpret_cast<const float4*>(&ylast[k]);
        const float4 wv = *reinterpret_cast<const float4*>(&wrow[k]);
        accb += v.x * wv.x + v.y * wv.y + v.z * wv.z + v.w * wv.w;
    }
    const float bh2 = b_hh_1b[g];
    if (g < 2 * H_) pre_rz[g] = accb + bh2;
    else            { gxn[g - 2 * H_] = accb; ghn[g - 2 * H_] = bh2; }
    __syncthreads();
    if (g < H_) {
        const float r = sigmoid_f(pre_rz[g]);
        const float z = sigmoid_f(pre_rz[g + H_]);
        const float n = tanh_f(gxn[g] + r * ghn[g]);
        hb[g] = (1.0f - z) * n;
    }
    __syncthreads();
    if (g < H_) red[g] = h1[b * H_ + g] * fc_w[g] + hb[g] * fc_w[H_ + g];
    __syncthreads();
    if (g == 0) {
        float s = fc_b[0];
#pragma unroll 8
        for (int k = 0; k < H_; ++k) s += red[k];
        out[b] = s;
    }
}

// ---------------------------------------------------------------------------
extern "C" void kernel_launch(void* const* d_in, const int* in_sizes, int n_in,
                              void* d_out, int out_size, void* d_ws, size_t ws_size,
                              hipStream_t stream)
{
    const float* seq      = (const float*)d_in[0];
    const float* w_ih_l0f = (const float*)d_in[1];
    const float* w_hh_l0f = (const float*)d_in[2];
    const float* b_ih_l0f = (const float*)d_in[3];
    const float* b_hh_l0f = (const float*)d_in[4];
    const float* w_ih_l0b = (const float*)d_in[5];
    const float* w_hh_l0b = (const float*)d_in[6];
    const float* b_ih_l0b = (const float*)d_in[7];
    const float* b_hh_l0b = (const float*)d_in[8];
    const float* w_ih_l1f = (const float*)d_in[9];
    const float* w_hh_l1f = (const float*)d_in[10];
    const float* b_ih_l1f = (const float*)d_in[11];
    const float* b_hh_l1f = (const float*)d_in[12];
    const float* w_ih_l1b = (const float*)d_in[13];
    // d_in[14] = w_hh_l1b unused: only t=T-1 of the reversed layer-1 backward
    // is needed, and there h0=0 -> gh = b_hh_l1b.
    const float* b_ih_l1b = (const float*)d_in[15];
    const float* b_hh_l1b = (const float*)d_in[16];
    const float* fc_w     = (const float*)d_in[17];
    const float* fc_b     = (const float*)d_in[18];
    float* out = (float*)d_out;

    __half* y0h = (__half*)d_ws;                               // 128 MiB
    __half* gxc = (__half*)((char*)d_ws +
                  (size_t)B_ * T_ * D1 * sizeof(__half));      // 24 MiB (f16)
    float*  h1  = (float*)(gxc + (size_t)B_ * CH * G3);        // 64 KiB

    hipLaunchKernelGGL(scan0_mfma3, dim3(16), dim3(256), 0, stream,
        seq, w_ih_l0f, w_hh_l0f, b_ih_l0f, b_hh_l0f,
             w_ih_l0b, w_hh_l0b, b_ih_l0b, b_hh_l0b, y0h);

    for (int ci = 0; ci < NCH; ++ci) {
        hipLaunchKernelGGL(gemm1_f16, dim3(B_ * CH / 128, 6), dim3(256), 0, stream,
            y0h, w_ih_l1f, b_ih_l1f, gxc, ci * CH);
        hipLaunchKernelGGL(scan1_mfma3, dim3(8), dim3(256), 0, stream,
            gxc, w_hh_l1f, b_hh_l1f, h1, ci);
    }

    hipLaunchKernelGGL(back1_fc, dim3(B_), dim3(384), 0, stream,
        y0h, h1, w_ih_l1b, b_ih_l1b, b_hh_l1b, fc_w, fc_b, out);
}